// Round 1
// baseline (688.376 us; speedup 1.0000x reference)
//
#include <hip/hip_runtime.h>
#include <hip/hip_bf16.h>

#define NN 50000
#define ECNT 800000
#define INCH 512
#define OUTCH 64

// ---------------- utility: zero an int array ----------------
__global__ void zero_kernel(int* __restrict__ p, int n) {
    int i = blockIdx.x * blockDim.x + threadIdx.x;
    if (i < n) p[i] = 0;
}

// ---------------- histogram of destination rows ----------------
__global__ void hist_kernel(const int* __restrict__ rows, int* __restrict__ deg, int n) {
    int e = blockIdx.x * blockDim.x + threadIdx.x;
    if (e < n) atomicAdd(&deg[rows[e]], 1);
}

// ---------------- single-block exclusive scan over N=50000 ints ----------------
__global__ __launch_bounds__(1024) void scan_kernel(const int* __restrict__ deg,
                                                    int* __restrict__ offs,
                                                    int* __restrict__ cursor, int n) {
    __shared__ int sd[1024];
    const int t = threadIdx.x;
    int carry = 0;
    for (int base = 0; base < n; base += 1024) {
        int idx = base + t;
        int v = (idx < n) ? deg[idx] : 0;
        sd[t] = v;
        __syncthreads();
        for (int off = 1; off < 1024; off <<= 1) {
            int y = (t >= off) ? sd[t - off] : 0;
            __syncthreads();
            sd[t] += y;
            __syncthreads();
        }
        int incl = sd[t];
        if (idx < n) {
            int ex = carry + incl - v;
            offs[idx] = ex;
            cursor[idx] = ex;
        }
        carry += sd[1023];
        __syncthreads();
    }
    if (t == 0) offs[n] = carry;  // == E
}

// ---------------- scatter edges into row-sorted CSR arrays ----------------
__global__ void scatter_kernel(const int* __restrict__ rows, const int* __restrict__ cols,
                               const float* __restrict__ vals, int* __restrict__ cursor,
                               int* __restrict__ colsOut, float* __restrict__ valsOut, int n) {
    int e = blockIdx.x * blockDim.x + threadIdx.x;
    if (e >= n) return;
    int r = rows[e];
    int p = atomicAdd(&cursor[r], 1);
    colsOut[p] = cols[e];
    valsOut[p] = vals[e];
}

// ---------------- dense projection: x0 = features @ W ----------------
// block = 256 threads = 4 waves; each wave computes 16 rows x 64 cols (lane = col)
__global__ __launch_bounds__(256) void gemm_kernel(const float* __restrict__ A,
                                                   const float* __restrict__ B,
                                                   float* __restrict__ C) {
    const int lane = threadIdx.x & 63;
    const int wave = threadIdx.x >> 6;
    const int r0 = blockIdx.x * 64 + wave * 16;

    int abase[16];
#pragma unroll
    for (int r = 0; r < 16; ++r) {
        int rr = r0 + r;
        if (rr > NN - 1) rr = NN - 1;   // clamp: loads stay in-bounds, writes guarded
        abase[r] = rr * INCH;
    }
    float acc[16];
#pragma unroll
    for (int r = 0; r < 16; ++r) acc[r] = 0.f;

    for (int k = 0; k < INCH; k += 4) {
        const float b0 = B[(k + 0) * OUTCH + lane];
        const float b1 = B[(k + 1) * OUTCH + lane];
        const float b2 = B[(k + 2) * OUTCH + lane];
        const float b3 = B[(k + 3) * OUTCH + lane];
#pragma unroll
        for (int r = 0; r < 16; ++r) {
            const float4 a = *reinterpret_cast<const float4*>(A + abase[r] + k);
            acc[r] = fmaf(a.x, b0, acc[r]);
            acc[r] = fmaf(a.y, b1, acc[r]);
            acc[r] = fmaf(a.z, b2, acc[r]);
            acc[r] = fmaf(a.w, b3, acc[r]);
        }
    }
#pragma unroll
    for (int r = 0; r < 16; ++r) {
        const int rr = r0 + r;
        if (rr < NN) C[(size_t)rr * OUTCH + lane] = acc[r];
    }
}

// ---------------- SpMM gather: xout[row] = sum_e val[e] * xin[col[e]] (+bias) ----------------
// one wave per row, lane = channel
__global__ __launch_bounds__(256) void spmm_kernel(const int* __restrict__ offs,
                                                   const int* __restrict__ cols,
                                                   const float* __restrict__ vals,
                                                   const float* __restrict__ xin,
                                                   float* __restrict__ xout,
                                                   const float* __restrict__ bias) {
    const int lane = threadIdx.x & 63;
    const int row = blockIdx.x * 4 + (threadIdx.x >> 6);
    if (row >= NN) return;
    const int s = offs[row];
    const int e = offs[row + 1];
    float acc = 0.f;
    int i = s;
    for (; i + 2 <= e; i += 2) {
        const int c0 = cols[i];
        const int c1 = cols[i + 1];
        const float v0 = vals[i];
        const float v1 = vals[i + 1];
        const float x0 = xin[(size_t)c0 * OUTCH + lane];
        const float x1 = xin[(size_t)c1 * OUTCH + lane];
        acc = fmaf(v0, x0, acc);
        acc = fmaf(v1, x1, acc);
    }
    if (i < e) {
        acc = fmaf(vals[i], xin[(size_t)cols[i] * OUTCH + lane], acc);
    }
    if (bias) acc += bias[lane];
    xout[(size_t)row * OUTCH + lane] = acc;
}

extern "C" void kernel_launch(void* const* d_in, const int* in_sizes, int n_in,
                              void* d_out, int out_size, void* d_ws, size_t ws_size,
                              hipStream_t stream) {
    const int*   adj   = (const int*)d_in[0];     // [2, E]: rows then cols
    const float* avals = (const float*)d_in[1];   // [E]
    const float* feat  = (const float*)d_in[2];   // [N, 512]
    const float* W     = (const float*)d_in[3];   // [512, 64]
    const float* bias  = (const float*)d_in[4];   // [64]
    float* out = (float*)d_out;

    const int E_ = in_sizes[1];                   // 800000
    const int* rows = adj;
    const int* cols = adj + E_;

    // workspace layout (all 4-byte aligned; x0 at offset 0 is 16B aligned)
    float* x0     = (float*)d_ws;                 // N*64 floats
    float* x1     = x0 + (size_t)NN * OUTCH;      // N*64 floats
    int*   deg    = (int*)(x1 + (size_t)NN * OUTCH);
    int*   offs   = deg + NN;                     // N+1
    int*   cursor = offs + NN + 1;                // N
    int*   cols_s = cursor + NN;                  // E
    float* vals_s = (float*)(cols_s + E_);        // E

    // ---- CSR build ----
    zero_kernel<<<(NN + 255) / 256, 256, 0, stream>>>(deg, NN);
    hist_kernel<<<(E_ + 255) / 256, 256, 0, stream>>>(rows, deg, E_);
    scan_kernel<<<1, 1024, 0, stream>>>(deg, offs, cursor, NN);
    scatter_kernel<<<(E_ + 255) / 256, 256, 0, stream>>>(rows, cols, avals, cursor,
                                                         cols_s, vals_s, E_);

    // ---- dense projection ----
    gemm_kernel<<<(NN + 63) / 64, 256, 0, stream>>>(feat, W, x0);

    // ---- two SpMM hops; bias fused into the last ----
    spmm_kernel<<<(NN + 3) / 4, 256, 0, stream>>>(offs, cols_s, vals_s, x0, x1, nullptr);
    spmm_kernel<<<(NN + 3) / 4, 256, 0, stream>>>(offs, cols_s, vals_s, x1, out, bias);
}

// Round 2
// 321.223 us; speedup vs baseline: 2.1430x; 2.1430x over previous
//
#include <hip/hip_runtime.h>
#include <hip/hip_bf16.h>

#define NN 50000
#define INCH 512
#define OUTCH 64
#define NB 196            // ceil(50000/256)

typedef __attribute__((ext_vector_type(8))) short short8;
typedef __attribute__((ext_vector_type(4))) float floatx4;

__device__ __forceinline__ unsigned short f2bf(float f) {
    unsigned u = __float_as_uint(f);
    return (unsigned short)((u + 0x7FFFu + ((u >> 16) & 1u)) >> 16);  // RNE
}

// ---------------- zero ----------------
__global__ void zero_kernel(int* __restrict__ p, int n) {
    int i = blockIdx.x * blockDim.x + threadIdx.x;
    if (i < n) p[i] = 0;
}

// ---------------- histogram of destination rows ----------------
__global__ void hist_kernel(const int* __restrict__ rows, int* __restrict__ deg, int n) {
    int e = blockIdx.x * blockDim.x + threadIdx.x;
    if (e < n) atomicAdd(&deg[rows[e]], 1);
}

// ---------------- hierarchical scan: block partial sums ----------------
__global__ __launch_bounds__(256) void partial_kernel(const int* __restrict__ deg,
                                                      int* __restrict__ bsum, int n) {
    int i = blockIdx.x * 256 + threadIdx.x;
    int v = (i < n) ? deg[i] : 0;
#pragma unroll
    for (int o = 32; o > 0; o >>= 1) v += __shfl_down(v, o, 64);
    __shared__ int ws[4];
    if ((threadIdx.x & 63) == 0) ws[threadIdx.x >> 6] = v;
    __syncthreads();
    if (threadIdx.x == 0) bsum[blockIdx.x] = ws[0] + ws[1] + ws[2] + ws[3];
}

// ---------------- scan the 196 partials (1 block) ----------------
__global__ __launch_bounds__(256) void scanpart_kernel(const int* __restrict__ bsum,
                                                       int* __restrict__ bpre,
                                                       int* __restrict__ offs, int Etot) {
    __shared__ int sd[256];
    const int t = threadIdx.x;
    int v = (t < NB) ? bsum[t] : 0;
    sd[t] = v;
    __syncthreads();
#pragma unroll
    for (int o = 1; o < 256; o <<= 1) {
        int y = (t >= o) ? sd[t - o] : 0;
        __syncthreads();
        sd[t] += y;
        __syncthreads();
    }
    if (t < NB) bpre[t] = sd[t] - v;     // exclusive
    if (t == 0) offs[NN] = Etot;
}

// ---------------- per-block rescan + add block prefix ----------------
__global__ __launch_bounds__(256) void scanfinal_kernel(const int* __restrict__ deg,
                                                        const int* __restrict__ bpre,
                                                        int* __restrict__ offs,
                                                        int* __restrict__ cursor, int n) {
    __shared__ int sd[256];
    const int t = threadIdx.x;
    const int i = blockIdx.x * 256 + t;
    int v = (i < n) ? deg[i] : 0;
    sd[t] = v;
    __syncthreads();
#pragma unroll
    for (int o = 1; o < 256; o <<= 1) {
        int y = (t >= o) ? sd[t - o] : 0;
        __syncthreads();
        sd[t] += y;
        __syncthreads();
    }
    if (i < n) {
        int ex = bpre[blockIdx.x] + sd[t] - v;
        offs[i] = ex;
        cursor[i] = ex;
    }
}

// ---------------- scatter edges into row-sorted packed array ----------------
__global__ void scatter_kernel(const int* __restrict__ rows, const int* __restrict__ cols,
                               const float* __restrict__ vals, int* __restrict__ cursor,
                               int2* __restrict__ edges, int n) {
    int e = blockIdx.x * blockDim.x + threadIdx.x;
    if (e >= n) return;
    int r = rows[e];
    int p = atomicAdd(&cursor[r], 1);
    edges[p] = make_int2(cols[e], __float_as_int(vals[e]));
}

// ---------------- dense projection: x0 = features @ W via bf16 MFMA ----------------
// block = 256 = 4 waves; tile 64 rows x 64 cols; K-chunks of 32, double-buffered LDS
#define LSTR 56   // LDS row stride in bf16 elements: 112 B = 7*16B (aligned, 2-way banks only)
__global__ __launch_bounds__(256) void gemm_mfma(const float* __restrict__ A,
                                                 const float* __restrict__ B,
                                                 float* __restrict__ C) {
    __shared__ unsigned short As[2][64 * LSTR];
    __shared__ unsigned short Bs[2][64 * LSTR];
    const int t = threadIdx.x;
    const int lane = t & 63;
    const int wave = t >> 6;
    const int r0 = blockIdx.x * 64;

    // A staging: row = t>>2 in [0,64), kpart = (t&3)*8
    const int a_row = t >> 2;
    const int a_k = (t & 3) * 8;
    int a_grow = r0 + a_row;
    if (a_grow >= NN) a_grow = NN - 1;          // clamp loads; stores guarded below
    const float* Ap = A + (size_t)a_grow * INCH + a_k;

    // B staging: n = lane, k-strip j = wave*8
    const int b_n = lane;
    const int b_j = wave * 8;

    float ar[8], br[8];
    // prologue: global loads for chunk 0
    {
        float4 v0 = *(const float4*)(Ap + 0);
        float4 v1 = *(const float4*)(Ap + 4);
        ar[0] = v0.x; ar[1] = v0.y; ar[2] = v0.z; ar[3] = v0.w;
        ar[4] = v1.x; ar[5] = v1.y; ar[6] = v1.z; ar[7] = v1.w;
#pragma unroll
        for (int i = 0; i < 8; ++i) br[i] = B[(b_j + i) * OUTCH + b_n];
    }
    // convert + store chunk 0 into buf 0
    {
        short8 av, bv;
#pragma unroll
        for (int i = 0; i < 8; ++i) { av[i] = (short)f2bf(ar[i]); bv[i] = (short)f2bf(br[i]); }
        *(short8*)&As[0][a_row * LSTR + a_k] = av;
        *(short8*)&Bs[0][b_n * LSTR + b_j] = bv;
    }

    floatx4 acc[4] = {floatx4{0,0,0,0}, floatx4{0,0,0,0}, floatx4{0,0,0,0}, floatx4{0,0,0,0}};
    const int frow = lane & 15;     // m (A) / n (B) index within fragment
    const int quad = lane >> 4;     // k-quad selector
    const int a_idx = (wave * 16 + frow) * LSTR + quad * 8;

    for (int c = 0; c < 16; ++c) {
        const int buf = c & 1;
        // issue global loads for chunk c+1 early (latency overlap with MFMA)
        if (c + 1 < 16) {
            const float* Ap2 = Ap + (c + 1) * 32;
            float4 v0 = *(const float4*)(Ap2 + 0);
            float4 v1 = *(const float4*)(Ap2 + 4);
            ar[0] = v0.x; ar[1] = v0.y; ar[2] = v0.z; ar[3] = v0.w;
            ar[4] = v1.x; ar[5] = v1.y; ar[6] = v1.z; ar[7] = v1.w;
            const int kb = (c + 1) * 32 + b_j;
#pragma unroll
            for (int i = 0; i < 8; ++i) br[i] = B[(kb + i) * OUTCH + b_n];
        }
        __syncthreads();   // staging of buf is complete
        short8 af = *(const short8*)&As[buf][a_idx];
#pragma unroll
        for (int f = 0; f < 4; ++f) {
            short8 bfr = *(const short8*)&Bs[buf][(f * 16 + frow) * LSTR + quad * 8];
            acc[f] = __builtin_amdgcn_mfma_f32_16x16x32_bf16(af, bfr, acc[f], 0, 0, 0);
        }
        if (c + 1 < 16) {
            short8 av, bv;
#pragma unroll
            for (int i = 0; i < 8; ++i) { av[i] = (short)f2bf(ar[i]); bv[i] = (short)f2bf(br[i]); }
            *(short8*)&As[buf ^ 1][a_row * LSTR + a_k] = av;
            *(short8*)&Bs[buf ^ 1][b_n * LSTR + b_j] = bv;
        }
    }

    // epilogue: C/D layout col = lane&15, row = quad*4 + reg   [m89]
#pragma unroll
    for (int f = 0; f < 4; ++f) {
#pragma unroll
        for (int reg = 0; reg < 4; ++reg) {
            const int row = r0 + wave * 16 + quad * 4 + reg;
            if (row < NN) C[(size_t)row * OUTCH + f * 16 + frow] = acc[f][reg];
        }
    }
}

// ---------------- SpMM gather: 4 rows per wave, 16 lanes x float4 per row ----------------
__global__ __launch_bounds__(256) void spmm_kernel(const int* __restrict__ offs,
                                                   const int2* __restrict__ edges,
                                                   const float* __restrict__ xin,
                                                   float* __restrict__ xout,
                                                   const float* __restrict__ bias) {
    const int t = threadIdx.x;
    const int lane = t & 63;
    const int sub = lane >> 4;          // row slot within wave
    const int c4 = (lane & 15) * 4;     // channel base
    const int row = blockIdx.x * 16 + (t >> 6) * 4 + sub;
    if (row >= NN) return;
    const int s = offs[row];
    const int e = offs[row + 1];
    float4 acc = make_float4(0.f, 0.f, 0.f, 0.f);
    int i = s;
    for (; i + 2 <= e; i += 2) {
        const int2 e0 = edges[i];
        const int2 e1 = edges[i + 1];
        const float4 x0 = *(const float4*)(xin + (size_t)e0.x * OUTCH + c4);
        const float4 x1 = *(const float4*)(xin + (size_t)e1.x * OUTCH + c4);
        const float v0 = __int_as_float(e0.y);
        const float v1 = __int_as_float(e1.y);
        acc.x = fmaf(v0, x0.x, acc.x); acc.y = fmaf(v0, x0.y, acc.y);
        acc.z = fmaf(v0, x0.z, acc.z); acc.w = fmaf(v0, x0.w, acc.w);
        acc.x = fmaf(v1, x1.x, acc.x); acc.y = fmaf(v1, x1.y, acc.y);
        acc.z = fmaf(v1, x1.z, acc.z); acc.w = fmaf(v1, x1.w, acc.w);
    }
    if (i < e) {
        const int2 e0 = edges[i];
        const float4 x0 = *(const float4*)(xin + (size_t)e0.x * OUTCH + c4);
        const float v0 = __int_as_float(e0.y);
        acc.x = fmaf(v0, x0.x, acc.x); acc.y = fmaf(v0, x0.y, acc.y);
        acc.z = fmaf(v0, x0.z, acc.z); acc.w = fmaf(v0, x0.w, acc.w);
    }
    if (bias) {
        const float4 bv = *(const float4*)(bias + c4);
        acc.x += bv.x; acc.y += bv.y; acc.z += bv.z; acc.w += bv.w;
    }
    *(float4*)(xout + (size_t)row * OUTCH + c4) = acc;
}

extern "C" void kernel_launch(void* const* d_in, const int* in_sizes, int n_in,
                              void* d_out, int out_size, void* d_ws, size_t ws_size,
                              hipStream_t stream) {
    const int*   adj   = (const int*)d_in[0];     // [2, E]
    const float* avals = (const float*)d_in[1];   // [E]
    const float* feat  = (const float*)d_in[2];   // [N, 512]
    const float* W     = (const float*)d_in[3];   // [512, 64]
    const float* bias  = (const float*)d_in[4];   // [64]
    float* out = (float*)d_out;

    const int E_ = in_sizes[1];
    const int* rows = adj;
    const int* cols = adj + E_;

    // workspace layout (16B-aligned segments)
    float* x0     = (float*)d_ws;                      // N*64 floats  (12.8 MB)
    float* x1     = x0 + (size_t)NN * OUTCH;           // N*64 floats  (12.8 MB)
    int2*  edges  = (int2*)(x1 + (size_t)NN * OUTCH);  // E int2       (6.4 MB), 8B-aligned
    int*   deg    = (int*)(edges + E_);                // N
    int*   offs   = deg + NN;                          // N+1
    int*   cursor = offs + NN + 1;                     // N
    int*   bsum   = cursor + NN;                       // NB
    int*   bpre   = bsum + NB;                         // NB

    // ---- CSR build ----
    zero_kernel<<<(NN + 255) / 256, 256, 0, stream>>>(deg, NN);
    hist_kernel<<<(E_ + 255) / 256, 256, 0, stream>>>(rows, deg, E_);
    partial_kernel<<<NB, 256, 0, stream>>>(deg, bsum, NN);
    scanpart_kernel<<<1, 256, 0, stream>>>(bsum, bpre, offs, E_);
    scanfinal_kernel<<<NB, 256, 0, stream>>>(deg, bpre, offs, cursor, NN);
    scatter_kernel<<<(E_ + 255) / 256, 256, 0, stream>>>(rows, cols, avals, cursor, edges, E_);

    // ---- dense projection (bf16 MFMA) ----
    gemm_mfma<<<(NN + 63) / 64, 256, 0, stream>>>(feat, W, x0);

    // ---- two SpMM hops; bias fused into the last ----
    spmm_kernel<<<(NN + 15) / 16, 256, 0, stream>>>(offs, edges, x0, x1, nullptr);
    spmm_kernel<<<(NN + 15) / 16, 256, 0, stream>>>(offs, edges, x1, out, bias);
}